// Round 4
// baseline (130.656 us; speedup 1.0000x reference)
//
#include <hip/hip_runtime.h>
#include <hip/hip_bf16.h>

// Shapes: B=8 C=512 T=32 H=W=7 P=49 N=8 E=64 K_WIN=7
// x: (B,C,T,H,W) fp32; out same fp32.

typedef float f32x4 __attribute__((ext_vector_type(4)));
typedef short s16x8 __attribute__((ext_vector_type(8)));
typedef short s16x4 __attribute__((ext_vector_type(4)));
typedef __bf16 bf16x8 __attribute__((ext_vector_type(8)));

static __device__ __forceinline__ float bf2f(unsigned short u){
  union { unsigned int i; float f; } x; x.i = ((unsigned int)u) << 16; return x.f;
}
static __device__ __forceinline__ unsigned short f2bf(float f){
  union { __hip_bfloat16 h; unsigned short u; } x; x.h = __float2bfloat16(f); return x.u;
}
static __device__ __forceinline__ f32x4 mfma16(s16x8 a, s16x8 b, f32x4 c){
  return __builtin_amdgcn_mfma_f32_16x16x32_bf16(
      __builtin_bit_cast(bf16x8, a), __builtin_bit_cast(bf16x8, b), c, 0, 0, 0);
}
static __device__ __forceinline__ void gload16(const unsigned short* g, unsigned short* l){
  __builtin_amdgcn_global_load_lds(
      (const __attribute__((address_space(1))) unsigned int*)g,
      (__attribute__((address_space(3))) unsigned int*)l, 16, 0, 0);
}
#define VMCNT(N) asm volatile("s_waitcnt vmcnt(" #N ")" ::: "memory")

// ---------------- per-channel stats -> scale/shift ----------------
__global__ __launch_bounds__(256) void stats_kernel(const float* __restrict__ x,
    const float* __restrict__ gamma, const float* __restrict__ beta,
    float* __restrict__ scale, float* __restrict__ shift){
  const int c = blockIdx.x, tid = threadIdx.x;
  float s1 = 0.f, s2 = 0.f;
  const float* xc = x + (size_t)c*1568;
  for (int i = tid; i < 3136; i += 256){
    int b = i / 392, j = i - b*392;
    f32x4 v = *(const f32x4*)(xc + (size_t)b*802816 + j*4);
    s1 += v[0]+v[1]+v[2]+v[3];
    s2 += v[0]*v[0]+v[1]*v[1]+v[2]*v[2]+v[3]*v[3];
  }
  #pragma unroll
  for (int off = 32; off > 0; off >>= 1){
    s1 += __shfl_down(s1, off);
    s2 += __shfl_down(s2, off);
  }
  __shared__ float r1[4], r2[4];
  int wave = tid >> 6, lane = tid & 63;
  if (lane == 0){ r1[wave] = s1; r2[wave] = s2; }
  __syncthreads();
  if (tid == 0){
    float t1 = r1[0]+r1[1]+r1[2]+r1[3];
    float t2 = r2[0]+r2[1]+r2[2]+r2[3];
    const float inv = 1.f/12544.f;
    float mean = t1*inv;
    float var  = t2*inv - mean*mean;
    float sc = gamma[c]*rsqrtf(var + 1e-5f);
    scale[c] = sc;
    shift[c] = beta[c] - mean*sc;
  }
}

// ---------------- pack weights to bf16 ----------------
__global__ __launch_bounds__(512) void pack_kernel(const float* __restrict__ Wq,
    const float* __restrict__ Wk, const float* __restrict__ Wv,
    const float* __restrict__ Wo, const float* __restrict__ bo,
    unsigned short* __restrict__ Wall, unsigned short* __restrict__ Wo2,
    float* __restrict__ bo_sum){
  int i = blockIdx.x*512 + threadIdx.x;
  if (i < 786432){
    const float* W = (i < 262144) ? Wq : (i < 524288 ? Wk : Wv);
    Wall[i] = f2bf(W[i & 262143]);
  } else if (i < 1048576){
    int j = i - 786432;
    int c = j >> 9, k = j & 511, nn = k >> 6, e = k & 63;
    Wo2[j] = f2bf(Wo[((size_t)nn*512 + c)*64 + e] * 0.125f);
  } else if (i < 1049088){
    int c = i - 1048576;
    float s = 0.f;
    #pragma unroll
    for (int nn = 0; nn < 8; ++nn) s += bo[nn*512 + c];
    bo_sum[c] = s * 0.125f;
  }
}

// ---------------- normalize + transpose x -> Xt[bt][p(64)][c(512)] bf16 ----------------
__global__ __launch_bounds__(256) void xt_kernel(const float* __restrict__ x,
    const float* __restrict__ scale, const float* __restrict__ shift,
    unsigned short* __restrict__ Xt){
  __shared__ unsigned short Xc[512][52];
  const int bt = blockIdx.x, b = bt >> 5, t = bt & 31, tid = threadIdx.x;
  const float* xb = x + (size_t)b*802816 + t*49;
  for (int i = tid; i < 512*49; i += 256){
    int c = i / 49, p = i - c*49;
    Xc[c][p] = f2bf(xb[(size_t)c*1568 + p]*scale[c] + shift[c]);
  }
  __syncthreads();
  unsigned short* dst = Xt + (size_t)bt*32768;
  for (int i = tid; i < 4096; i += 256){
    int p = i & 63, c0 = (i >> 6) << 3;
    s16x8 v;
    #pragma unroll
    for (int j = 0; j < 8; ++j) v[j] = (p < 49) ? (short)Xc[c0+j][p] : (short)0;
    *(s16x8*)(dst + p*512 + c0) = v;
  }
}

// ---------------- QKV as tiled MFMA GEMM, 4-deep ring + counted vmcnt ----------------
// Wall(1536x512) x Xt^T(512x16384). 128x128 tiles, BK=32.
__global__ __launch_bounds__(256) void qkv_gemm(const unsigned short* __restrict__ Wall,
    const unsigned short* __restrict__ Xt,
    const float* __restrict__ bq, const float* __restrict__ bk, const float* __restrict__ bv,
    unsigned short* __restrict__ Qg, unsigned short* __restrict__ Kg,
    unsigned short* __restrict__ Vg){
  __shared__ unsigned short As[4][4096];
  __shared__ unsigned short Bs[4][4096];
  const int bid = blockIdx.x;
  const int id = (bid & 7)*192 + (bid >> 3);   // XCD-chunked (1536%8==0)
  const int bm = id % 12, bn = id / 12;        // bm fastest: A cycles, B L2-chunk
  const int m0 = bm*128, n0 = bn*128;
  const int tid = threadIdx.x;
  const int w = __builtin_amdgcn_readfirstlane(tid >> 6);
  const int lane = tid & 63, l15 = lane & 15, g = lane >> 4, g4 = (lane >> 4)*4;
  const int wm = w >> 1, wn = w & 1;
  const int cA = w*128 + lane;
  int offA[4], offB[4];
  #pragma unroll
  for (int mi = 0; mi < 4; ++mi){
    int row = wm*64 + mi*16 + l15;
    offA[mi] = row*32 + ((g ^ ((row>>1)&3))<<3);
  }
  #pragma unroll
  for (int ni = 0; ni < 4; ++ni){
    int col = wn*64 + ni*16 + l15;
    offB[ni] = col*32 + ((g ^ ((col>>1)&3))<<3);
  }
  f32x4 acc[4][4];
  #pragma unroll
  for (int mi = 0; mi < 4; ++mi)
    #pragma unroll
    for (int ni = 0; ni < 4; ++ni) acc[mi][ni] = 0.f;

  auto stage = [&](int bufi, int ks){
    #pragma unroll
    for (int it = 0; it < 2; ++it){
      int c = cA + it*64;
      int row = c >> 2, slot = c & 3;
      int ko = ks*32 + ((slot ^ ((row>>1)&3))<<3);
      gload16(Wall + (size_t)(m0 + row)*512 + ko, &As[bufi][(w*128 + it*64)*8]);
      gload16(Xt   + (size_t)(n0 + row)*512 + ko, &Bs[bufi][(w*128 + it*64)*8]);
    }
  };
  auto compute = [&](int bufi){
    s16x8 Af[4], Bf[4];
    #pragma unroll
    for (int mi = 0; mi < 4; ++mi) Af[mi] = *(const s16x8*)&As[bufi][offA[mi]];
    #pragma unroll
    for (int ni = 0; ni < 4; ++ni) Bf[ni] = *(const s16x8*)&Bs[bufi][offB[ni]];
    #pragma unroll
    for (int mi = 0; mi < 4; ++mi)
      #pragma unroll
      for (int ni = 0; ni < 4; ++ni)
        acc[mi][ni] = mfma16(Af[mi], Bf[ni], acc[mi][ni]);
  };

  stage(0, 0); stage(1, 1); stage(2, 2);      // 12 loads in flight
  #pragma unroll 1
  for (int j = 0; j < 13; ++j){
    VMCNT(8);                                  // stage(j) landed
    __builtin_amdgcn_s_barrier();
    __builtin_amdgcn_sched_barrier(0);
    stage((j+3) & 3, j+3);                     // overwrites buf(j-1): safe post-barrier
    __builtin_amdgcn_s_setprio(1);
    compute(j & 3);
    __builtin_amdgcn_s_setprio(0);
  }
  VMCNT(8);  __builtin_amdgcn_s_barrier(); __builtin_amdgcn_sched_barrier(0);
  __builtin_amdgcn_s_setprio(1); compute(1); __builtin_amdgcn_s_setprio(0);
  VMCNT(4);  __builtin_amdgcn_s_barrier(); __builtin_amdgcn_sched_barrier(0);
  __builtin_amdgcn_s_setprio(1); compute(2); __builtin_amdgcn_s_setprio(0);
  VMCNT(0);  __builtin_amdgcn_s_barrier(); __builtin_amdgcn_sched_barrier(0);
  __builtin_amdgcn_s_setprio(1); compute(3); __builtin_amdgcn_s_setprio(0);

  // epilogue: wave quadrant = one (which, head, bt)
  const int qb = bm*2 + wm;            // 0..23
  const int which = qb >> 3, n = qb & 7;
  const int bt = bn*2 + wn, b = bt >> 5, t = bt & 31;
  const size_t bnt = ((size_t)(b*8 + n)*32 + t);
  const float* bias = which == 0 ? bq : (which == 1 ? bk : bv);
  #pragma unroll
  for (int mi = 0; mi < 4; ++mi){
    const int e0 = mi*16 + g4;
    const f32x4 bb = *(const f32x4*)(bias + n*64 + e0);
    #pragma unroll
    for (int ni = 0; ni < 4; ++ni){
      const int p = ni*16 + l15;
      f32x4 v = acc[mi][ni] + bb;
      if (which == 0) v *= 1.4426950408889634f;
      if (p < 49){
        if (which < 2){
          s16x4 u;
          #pragma unroll
          for (int r = 0; r < 4; ++r) u[r] = (short)f2bf(v[r]);
          *(s16x4*)((which == 0 ? Qg : Kg) + (bnt*49 + p)*64 + e0) = u;
        } else {
          #pragma unroll
          for (int r = 0; r < 4; ++r)
            Vg[bnt*3328 + (size_t)(e0 + r)*52 + p] = f2bf(v[r]);
        }
      }
    }
  }
}

// ---------------- local attention (MFMA, online softmax in registers) ----------------
__global__ __launch_bounds__(512,2) void attn_kernel(const unsigned short* __restrict__ Qg,
    const unsigned short* __restrict__ Kg, const unsigned short* __restrict__ Vg,
    const float* __restrict__ bk, const float* __restrict__ bv,
    unsigned short* __restrict__ Yg){
  const int bid = blockIdx.x;
  const int bt = ((bid & 7) << 5) | (bid >> 3);
  const int b = bt >> 5, t = bt & 31, tid = threadIdx.x;
  const int n = __builtin_amdgcn_readfirstlane(tid >> 6);
  const int lane = tid & 63, g = lane >> 4, l15 = lane & 15, g4 = (lane >> 4)*4;
  const size_t bnt = ((size_t)(b*8 + n)*32 + t);
  const unsigned short* Qb = Qg + bnt*3136;
  s16x8 Qf[4][2];
  #pragma unroll
  for (int ni = 0; ni < 4; ++ni)
    #pragma unroll
    for (int ks = 0; ks < 2; ++ks)
      Qf[ni][ks] = *(const s16x8*)(Qb + (ni*16 + l15)*64 + ks*32 + g*8);
  const float* bkp = bk + n*64;
  f32x4 bkf[2][2];
  bkf[0][0] = *(const f32x4*)(bkp + g*8);      bkf[0][1] = *(const f32x4*)(bkp + g*8 + 4);
  bkf[1][0] = *(const f32x4*)(bkp + 32 + g*8); bkf[1][1] = *(const f32x4*)(bkp + 32 + g*8 + 4);
  float pad_l[4];
  #pragma unroll
  for (int ni = 0; ni < 4; ++ni){
    float s = 0.f;
    #pragma unroll
    for (int ks = 0; ks < 2; ++ks)
      #pragma unroll
      for (int h = 0; h < 2; ++h)
        #pragma unroll
        for (int j = 0; j < 4; ++j)
          s += bf2f((unsigned short)Qf[ni][ks][h*4+j]) * bkf[ks][h][j];
    s += __shfl_xor(s, 16); s += __shfl_xor(s, 32);
    pad_l[ni] = s;
  }
  float m_run[4], d_run[4];
  f32x4 Yacc[4][4];
  #pragma unroll
  for (int ni = 0; ni < 4; ++ni){
    m_run[ni] = -1e30f; d_run[ni] = 0.f;
    #pragma unroll
    for (int me = 0; me < 4; ++me) Yacc[me][ni] = 0.f;
  }
  int slo = 3 - t; if (slo < 0) slo = 0;
  int shi = 34 - t; if (shi > 6) shi = 6;
  for (int s = slo; s <= shi; ++s){
    const int tt = t + s - 3;
    const unsigned short* Kb = Kg + ((size_t)(b*8 + n)*32 + tt)*3136;
    const unsigned short* Vb = Vg + ((size_t)(b*8 + n)*32 + tt)*3328;
    f32x4 S[4][4];
    #pragma unroll
    for (int mi = 0; mi < 4; ++mi)
      #pragma unroll
      for (int ni = 0; ni < 4; ++ni) S[mi][ni] = 0.f;
    __builtin_amdgcn_s_setprio(1);
    #pragma unroll
    for (int ks = 0; ks < 2; ++ks)
      #pragma unroll
      for (int mi = 0; mi < 4; ++mi){
        s16x8 Kf = *(const s16x8*)(Kb + (mi*16 + l15)*64 + ks*32 + g*8);
        #pragma unroll
        for (int ni = 0; ni < 4; ++ni)
          S[mi][ni] = mfma16(Kf, Qf[ni][ks], S[mi][ni]);
      }
    __builtin_amdgcn_s_setprio(0);
    #pragma unroll
    for (int r = 0; r < 4; ++r){
      const bool bad = (g4 + r) >= 1;
      #pragma unroll
      for (int ni = 0; ni < 4; ++ni)
        S[3][ni][r] = bad ? -1e30f : S[3][ni][r];
    }
    #pragma unroll
    for (int ni = 0; ni < 4; ++ni){
      float mx = -1e30f;
      #pragma unroll
      for (int mi = 0; mi < 4; ++mi)
        #pragma unroll
        for (int r = 0; r < 4; ++r) mx = fmaxf(mx, S[mi][ni][r]);
      mx = fmaxf(mx, __shfl_xor(mx, 16));
      mx = fmaxf(mx, __shfl_xor(mx, 32));
      const float mn = fmaxf(m_run[ni], mx);
      const float rs = exp2f(m_run[ni] - mn);
      m_run[ni] = mn;
      float sum = 0.f;
      #pragma unroll
      for (int mi = 0; mi < 4; ++mi)
        #pragma unroll
        for (int r = 0; r < 4; ++r){
          float e = exp2f(S[mi][ni][r] - mn);
          S[mi][ni][r] = e; sum += e;
        }
      sum += __shfl_xor(sum, 16); sum += __shfl_xor(sum, 32);
      d_run[ni] = d_run[ni]*rs + sum;
      #pragma unroll
      for (int me = 0; me < 4; ++me) Yacc[me][ni] *= rs;
    }
    #pragma unroll
    for (int ks = 0; ks < 2; ++ks){
      s16x8 Pf[4];
      #pragma unroll
      for (int ni = 0; ni < 4; ++ni){
        f32x4 a = S[2*ks][ni], b2 = S[2*ks+1][ni];
        s16x8 pf;
        #pragma unroll
        for (int j = 0; j < 4; ++j){
          pf[j]   = (short)f2bf(a[j]);
          pf[4+j] = (short)f2bf(b2[j]);
        }
        Pf[ni] = pf;
      }
      __builtin_amdgcn_s_setprio(1);
      #pragma unroll
      for (int me = 0; me < 4; ++me){
        s16x4 vlo = *(const s16x4*)(Vb + (size_t)(me*16 + l15)*52 + ks*32 + g4);
        s16x4 vhi = *(const s16x4*)(Vb + (size_t)(me*16 + l15)*52 + ks*32 + 16 + g4);
        s16x8 Vf;
        #pragma unroll
        for (int j = 0; j < 4; ++j){ Vf[j] = vlo[j]; Vf[4+j] = vhi[j]; }
        #pragma unroll
        for (int ni = 0; ni < 4; ++ni)
          Yacc[me][ni] = mfma16(Vf, Pf[ni], Yacc[me][ni]);
      }
      __builtin_amdgcn_s_setprio(0);
    }
  }
  const int n_pad = slo + (6 - shi);
  f32x4 bvf[4];
  #pragma unroll
  for (int me = 0; me < 4; ++me)
    bvf[me] = *(const f32x4*)(bv + n*64 + me*16 + g4);
  unsigned short* Yb = Yg + bnt*3136;
  #pragma unroll
  for (int ni = 0; ni < 4; ++ni){
    float rs = 1.f, pw = 0.f, d = d_run[ni];
    if (n_pad > 0){
      const float mf = fmaxf(m_run[ni], pad_l[ni]);
      rs = exp2f(m_run[ni] - mf);
      pw = (float)(n_pad*49) * exp2f(pad_l[ni] - mf);
      d = d_run[ni]*rs + pw;
    }
    const float inv = 1.f/d;
    const int p = ni*16 + l15;
    if (p < 49){
      #pragma unroll
      for (int me = 0; me < 4; ++me){
        s16x4 u;
        #pragma unroll
        for (int r = 0; r < 4; ++r)
          u[r] = (short)f2bf((Yacc[me][ni][r]*rs + pw*bvf[me][r])*inv);
        *(s16x4*)(Yb + (size_t)p*64 + me*16 + g4) = u;
      }
    }
  }
}

// ---------------- output projection as tiled MFMA GEMM (4-deep ring) ----------------
__global__ __launch_bounds__(256) void out_gemm(const unsigned short* __restrict__ Wo2,
    const unsigned short* __restrict__ Yg, const unsigned short* __restrict__ Xt,
    const float* __restrict__ scale, const float* __restrict__ shift,
    const float* __restrict__ bo_sum, float* __restrict__ out){
  __shared__ unsigned short As[4][4096];
  __shared__ unsigned short Bs[4][4096];
  const int bid = blockIdx.x;
  const int id = (bid & 7)*64 + (bid >> 3);    // 512%8==0
  const int bm = id % 4, bn = id / 4;
  const int m0 = bm*128, n0 = bn*128;
  const int tid = threadIdx.x;
  const int w = __builtin_amdgcn_readfirstlane(tid >> 6);
  const int lane = tid & 63, l15 = lane & 15, g = lane >> 4, g4 = (lane >> 4)*4;
  const int wm = w >> 1, wn = w & 1;
  const int cA = w*128 + lane;
  int offA[4], offB[4];
  #pragma unroll
  for (int mi = 0; mi < 4; ++mi){
    int row = wm*64 + mi*16 + l15;
    offA[mi] = row*32 + ((g ^ ((row>>1)&3))<<3);
  }
  #pragma unroll
  for (int ni = 0; ni < 4; ++ni){
    int col = wn*64 + ni*16 + l15;
    offB[ni] = col*32 + ((g ^ ((col>>1)&3))<<3);
  }
  f32x4 acc[4][4];
  #pragma unroll
  for (int mi = 0; mi < 4; ++mi)
    #pragma unroll
    for (int ni = 0; ni < 4; ++ni) acc[mi][ni] = 0.f;

  auto stage = [&](int bufi, int ks){
    const int nh = ks >> 1, eo = (ks & 1)*32;
    #pragma unroll
    for (int it = 0; it < 2; ++it){
      int c = cA + it*64;
      int row = c >> 2, slot = c & 3;
      int sw = ((slot ^ ((row>>1)&3))<<3);
      gload16(Wo2 + (size_t)(m0 + row)*512 + ks*32 + sw, &As[bufi][(w*128 + it*64)*8]);
      const int col = n0 + row, btc = col >> 6, p = col & 63;
      const size_t bb = ((size_t)((btc >> 5)*8 + nh)*32 + (btc & 31));
      gload16(Yg + bb*3136 + p*64 + eo + sw, &Bs[bufi][(w*128 + it*64)*8]);
    }
  };
  auto compute = [&](int bufi){
    s16x8 Af[4], Bf[4];
    #pragma unroll
    for (int mi = 0; mi < 4; ++mi) Af[mi] = *(const s16x8*)&As[bufi][offA[mi]];
    #pragma unroll
    for (int ni = 0; ni < 4; ++ni) Bf[ni] = *(const s16x8*)&Bs[bufi][offB[ni]];
    #pragma unroll
    for (int mi = 0; mi < 4; ++mi)
      #pragma unroll
      for (int ni = 0; ni < 4; ++ni)
        acc[mi][ni] = mfma16(Af[mi], Bf[ni], acc[mi][ni]);
  };

  stage(0, 0); stage(1, 1); stage(2, 2);
  #pragma unroll 1
  for (int j = 0; j < 13; ++j){
    VMCNT(8);
    __builtin_amdgcn_s_barrier();
    __builtin_amdgcn_sched_barrier(0);
    stage((j+3) & 3, j+3);
    __builtin_amdgcn_s_setprio(1);
    compute(j & 3);
    __builtin_amdgcn_s_setprio(0);
  }
  VMCNT(8);  __builtin_amdgcn_s_barrier(); __builtin_amdgcn_sched_barrier(0);
  __builtin_amdgcn_s_setprio(1); compute(1); __builtin_amdgcn_s_setprio(0);
  VMCNT(4);  __builtin_amdgcn_s_barrier(); __builtin_amdgcn_sched_barrier(0);
  __builtin_amdgcn_s_setprio(1); compute(2); __builtin_amdgcn_s_setprio(0);
  VMCNT(0);  __builtin_amdgcn_s_barrier(); __builtin_amdgcn_sched_barrier(0);
  __builtin_amdgcn_s_setprio(1); compute(3); __builtin_amdgcn_s_setprio(0);

  const int cb = m0 + wm*64;
  const int bt = bn*2 + wn, b = bt >> 5, t = bt & 31;
  const unsigned short* XtB = Xt + (size_t)bt*32768;
  #pragma unroll
  for (int mi = 0; mi < 4; ++mi){
    const int c0 = cb + mi*16 + g4;
    const f32x4 sc = *(const f32x4*)(bo_sum + c0);
    #pragma unroll
    for (int ni = 0; ni < 4; ++ni){
      const int p = ni*16 + l15;
      if (p < 49){
        s16x4 xb = *(const s16x4*)(XtB + p*512 + c0);
        #pragma unroll
        for (int r = 0; r < 4; ++r){
          const int c = c0 + r;
          out[((size_t)(b*512 + c))*1568 + t*49 + p] =
              acc[mi][ni][r] + sc[r] + bf2f((unsigned short)xb[r]);
        }
      }
    }
  }
}

extern "C" void kernel_launch(void* const* d_in, const int* in_sizes, int n_in_,
                              void* d_out, int out_size, void* d_ws, size_t ws_size,
                              hipStream_t stream){
  const float* x     = (const float*)d_in[0];
  const float* gamma = (const float*)d_in[1];
  const float* beta  = (const float*)d_in[2];
  const float* Wq    = (const float*)d_in[3];
  const float* bq    = (const float*)d_in[4];
  const float* Wk    = (const float*)d_in[5];
  const float* bk    = (const float*)d_in[6];
  const float* Wv    = (const float*)d_in[7];
  const float* bv    = (const float*)d_in[8];
  const float* Wo    = (const float*)d_in[9];
  const float* bo    = (const float*)d_in[10];
  float* out = (float*)d_out;

  char* ws = (char*)d_ws;
  float* scale  = (float*)ws;            // 512
  float* shift  = scale + 512;           // 512
  float* bo_sum = shift + 512;           // 512
  unsigned short* Wall = (unsigned short*)(ws + 8192);
  const size_t PAD = 16384;
  unsigned short* Wo2 = Wall + 786432;
  unsigned short* Xt  = Wo2 + 262144;
  unsigned short* Qg  = Xt + 8388608;
  unsigned short* Kg  = Qg + 6422528 + PAD;
  unsigned short* Vg  = Kg + 6422528 + PAD;
  unsigned short* Yg  = Vg + 6815744 + PAD;

  hipLaunchKernelGGL(stats_kernel, dim3(512), dim3(256), 0, stream,
                     x, gamma, beta, scale, shift);
  hipLaunchKernelGGL(pack_kernel, dim3(2049), dim3(512), 0, stream,
                     Wq, Wk, Wv, Wo, bo, Wall, Wo2, bo_sum);
  hipLaunchKernelGGL(xt_kernel, dim3(256), dim3(256), 0, stream,
                     x, scale, shift, Xt);
  hipLaunchKernelGGL(qkv_gemm, dim3(1536), dim3(256), 0, stream,
                     Wall, Xt, bq, bk, bv, Qg, Kg, Vg);
  hipLaunchKernelGGL(attn_kernel, dim3(256), dim3(512), 0, stream,
                     Qg, Kg, Vg, bk, bv, Yg);
  hipLaunchKernelGGL(out_gemm, dim3(512), dim3(256), 0, stream,
                     Wo2, Yg, Xt, scale, shift, bo_sum, out);
}